// Round 4
// baseline (2041.192 us; speedup 1.0000x reference)
//
#include <hip/hip_runtime.h>
#include <hip/hip_bf16.h>
#include <stdint.h>

typedef __hip_bfloat16 bf;
__device__ __forceinline__ float b2f(bf x){ return __bfloat162float(x); }
// clamp that also launders NaN to a finite value (IEEE min/max return the non-NaN operand)
__device__ __forceinline__ float sane(float x){ return fminf(fmaxf(x, -1e6f), 1e6f); }

// Problem constants (fixed by the reference)
constexpr int N   = 6144;          // NOT a power of two (3*2^11)!
constexpr int D   = 64;
constexpr int FE  = 32;
constexpr int Eg  = 196608;
constexpr int CH  = 2;             // attention column chunks
constexpr int JC  = N / CH;        // 3072 cols per chunk
constexpr int RG  = N / 64;        // 96 row groups (lane = row within group)
constexpr int MW  = JC / 32;       // 96 mask words per row per chunk
constexpr size_t NF = (size_t)N * D;

__device__ __forceinline__ int clampi(int v){ return v < 0 ? 0 : (v >= N ? N - 1 : v); }
// dtype-adaptive load: isf32 selects float32 vs bf16 interpretation
__device__ __forceinline__ float ldf(const void* p, size_t i, uint32_t isf32){
    return isf32 ? ((const float*)p)[i] : b2f(((const bf*)p)[i]);
}

// ---- float workspace layout (floats) ----  total 5,529,600 floats = 22.1 MB
constexpr size_t OF_QKV   = 0;                            // [6][N][D]  Qp,Kp,Vp,Qn,Kn,Vn
constexpr size_t OF_OPART = OF_QKV + 6 * NF;              // [2][CH][N][D]
constexpr size_t OF_LPART = OF_OPART + (size_t)2*CH*NF;   // [2][CH][N]
constexpr size_t OF_MEAN  = OF_LPART + (size_t)2*CH*N;    // [2][N][D]
constexpr size_t OF_POOL  = OF_MEAN + 2*NF;               // [4][N][FE]
constexpr size_t F_TOTAL  = OF_POOL + (size_t)4*N*FE;
// ---- u32 workspace layout (words, after float region) ----  ~3.44 MB
constexpr size_t OI_CNT  = 0;                             // [4][N]
constexpr size_t OI_PTR  = OI_CNT + 4*(size_t)N;          // [4][N+1]
constexpr size_t OI_CUR  = OI_PTR + 4*(size_t)(N+1);      // [4][N]
constexpr size_t OI_EID  = OI_CUR + 4*(size_t)N;          // [4][Eg]
constexpr size_t OI_FLAG = OI_EID + 4*(size_t)Eg;         // [4] dtype flags

__global__ void zero_kernel(uint32_t* __restrict__ p, int n){
    int i = blockIdx.x * 256 + threadIdx.x;
    if (i < n) p[i] = 0u;
}

// dtype sniff: read tensors AS bf16; true-bf16 data has max|v|<~6, f32 data
// misread as bf16 has random exponents -> max|v| >> 100 over 4096 samples.
__global__ void sniff_kernel(const void* xA, const void* xB, const void* xC, const void* xD,
                             uint32_t* __restrict__ flags){
    __shared__ float red[256];
    const void* ps[4] = {xA, xB, xC, xD};
    int t = threadIdx.x;
    for (int k = 0; k < 4; ++k){
        const bf* p = (const bf*)ps[k];
        float m = 0.f;
        for (int i = t; i < 4096; i += 256){
            float v = fabsf(b2f(p[i]));
            if (!(v <= 1e9f)) v = 1e9f;        // NaN/inf -> big
            m = fmaxf(m, v);
        }
        red[t] = m; __syncthreads();
        for (int off = 128; off; off >>= 1){
            if (t < off) red[t] = fmaxf(red[t], red[t + off]);
            __syncthreads();
        }
        if (t == 0) flags[k] = (red[0] > 100.f) ? 1u : 0u;   // 1 = float32
        __syncthreads();
    }
}

// out[i][c] = sum_d x[i][d] * W[d][c] + b[c]   (f32 accumulate, f32 out to ws)
__global__ void qkv_kernel(const void* __restrict__ x1, const void* __restrict__ x2,
                           const void* __restrict__ W0, const void* __restrict__ W1,
                           const void* __restrict__ W2, const void* __restrict__ W3,
                           const void* __restrict__ W4, const void* __restrict__ W5,
                           const void* __restrict__ B0, const void* __restrict__ B1,
                           const void* __restrict__ B2, const void* __restrict__ B3,
                           const void* __restrict__ B4, const void* __restrict__ B5,
                           const uint32_t* __restrict__ flags, float* __restrict__ ws){
    uint32_t fA = flags[0], fD = flags[3];
    int m = blockIdx.y;
    int wid = threadIdx.x >> 6, lane = threadIdx.x & 63;
    int i = blockIdx.x * 4 + wid;
    const void* x = (m < 3) ? x1 : x2;
    const void* W = (m==0)?W0:(m==1)?W1:(m==2)?W2:(m==3)?W3:(m==4)?W4:W5;
    const void* B = (m==0)?B0:(m==1)?B1:(m==2)?B2:(m==3)?B3:(m==4)?B4:B5;
    float acc = ldf(B, lane, fD);
    #pragma unroll 8
    for (int d = 0; d < D; ++d)
        acc += ldf(x, (size_t)i * D + d, fA) * ldf(W, (size_t)d * D + lane, fD);
    ws[OF_QKV + (size_t)m * NF + (size_t)i * D + lane] = sane(acc);
}

// CSR degree counts (4 CSRs: pos-row, pos-col, neg-row, neg-col)
__global__ void count_kernel(const int* __restrict__ eip, const int* __restrict__ ein,
                             uint32_t* __restrict__ iws){
    int e = blockIdx.x * 256 + threadIdx.x;
    if (e >= Eg) return;
    uint32_t* cnt = iws + OI_CNT;
    atomicAdd(&cnt[0 * N + clampi(eip[e])],      1u);
    atomicAdd(&cnt[1 * N + clampi(eip[Eg + e])], 1u);
    atomicAdd(&cnt[2 * N + clampi(ein[e])],      1u);
    atomicAdd(&cnt[3 * N + clampi(ein[Eg + e])], 1u);
}

// exclusive scan of one CSR's counts (one block per CSR); also seeds cursors
__global__ void scan_kernel(uint32_t* __restrict__ iws){
    int b = blockIdx.x, t = threadIdx.x;
    const uint32_t* c = iws + OI_CNT + (size_t)b * N;
    uint32_t* P  = iws + OI_PTR + (size_t)b * (N + 1);
    uint32_t* Cu = iws + OI_CUR + (size_t)b * N;
    constexpr int K = N / 256;   // 24
    int base = t * K;
    uint32_t s = 0;
    for (int k = 0; k < K; ++k) s += c[base + k];
    __shared__ uint32_t sums[256];
    sums[t] = s; __syncthreads();
    for (int off = 1; off < 256; off <<= 1){
        uint32_t v = (t >= off) ? sums[t - off] : 0u;
        __syncthreads();
        sums[t] += v;
        __syncthreads();
    }
    uint32_t run = (t == 0) ? 0u : sums[t - 1];
    for (int k = 0; k < K; ++k){ P[base + k] = run; Cu[base + k] = run; run += c[base + k]; }
    if (t == 255) P[N] = run;
}

__global__ void fill_kernel(const int* __restrict__ eip, const int* __restrict__ ein,
                            uint32_t* __restrict__ iws){
    int e = blockIdx.x * 256 + threadIdx.x;
    if (e >= Eg) return;
    uint32_t* Cu  = iws + OI_CUR;
    uint32_t* Eid = iws + OI_EID;
    int rp = clampi(eip[e]), cp = clampi(eip[Eg + e]);
    int rn = clampi(ein[e]), cn = clampi(ein[Eg + e]);
    uint32_t p;
    p = atomicAdd(&Cu[0 * N + rp], 1u); if (p < Eg) Eid[0 * (size_t)Eg + p] = (uint32_t)e;
    p = atomicAdd(&Cu[1 * N + cp], 1u); if (p < Eg) Eid[1 * (size_t)Eg + p] = (uint32_t)e;
    p = atomicAdd(&Cu[2 * N + rn], 1u); if (p < Eg) Eid[2 * (size_t)Eg + p] = (uint32_t)e;
    p = atomicAdd(&Cu[3 * N + cn], 1u); if (p < Eg) Eid[3 * (size_t)Eg + p] = (uint32_t)e;
}

// neighbor mean (with self loop), wave per (sign,node), lane = feature dim
__global__ void mean_kernel(const void* __restrict__ x1, const void* __restrict__ x2,
                            const int* __restrict__ eip, const int* __restrict__ ein,
                            const uint32_t* __restrict__ iws,
                            const uint32_t* __restrict__ flags, float* __restrict__ ws){
    uint32_t fA = flags[0];
    int wid = threadIdx.x >> 6, d = threadIdx.x & 63;
    int gw = blockIdx.x * 4 + wid;
    int sign = gw >= N;
    int i = gw - sign * N;
    const void* x = sign ? x2 : x1;
    const int* ei = sign ? ein : eip;
    int csr = sign ? 2 : 0;
    const uint32_t* P   = iws + OI_PTR + (size_t)csr * (N + 1);
    const uint32_t* Eid = iws + OI_EID + (size_t)csr * Eg;
    float acc = ldf(x, (size_t)i * D + d, fA);   // self loop
    uint32_t p0 = P[i], p1 = P[i + 1];
    if (p1 > (uint32_t)Eg) p1 = Eg;
    if (p0 > p1) p0 = p1;
    for (uint32_t p = p0; p < p1; ++p){
        uint32_t e = Eid[p]; if (e >= Eg) e = 0;
        int c = clampi(ei[Eg + e]);
        acc += ldf(x, (size_t)c * D + d, fA);
    }
    ws[OF_MEAN + (size_t)sign * NF + (size_t)i * D + d] = sane(acc / (float)(p1 - p0 + 1));
}

// per-node max-pool of edge features (by row/col, per sign) + L2 normalize
__global__ void pool_kernel(const void* __restrict__ efp, const void* __restrict__ efn,
                            const uint32_t* __restrict__ iws,
                            const uint32_t* __restrict__ flags, float* __restrict__ ws){
    uint32_t fB = flags[1];
    int wid = threadIdx.x >> 6, lane = threadIdx.x & 63;
    int gw = blockIdx.x * 4 + wid;
    int g = gw / N, i = gw - g * N;
    const void* ef = (g < 2) ? efp : efn;
    const uint32_t* P   = iws + OI_PTR + (size_t)g * (N + 1);
    const uint32_t* Eid = iws + OI_EID + (size_t)g * Eg;
    int f = lane & 31, h = lane >> 5;
    float m = 0.f;                            // feats are uniform[0,1) >= 0
    uint32_t p0 = P[i], p1 = P[i + 1];
    if (p1 > (uint32_t)Eg) p1 = Eg;
    if (p0 > p1) p0 = p1;
    for (uint32_t p = p0 + h; p < p1; p += 2){
        uint32_t e = Eid[p]; if (e >= Eg) e = 0;
        m = fmaxf(m, ldf(ef, (size_t)e * FE + f, fB));
    }
    m = fmaxf(m, __shfl_xor(m, 32, 64));      // combine the two half-lanes
    m = sane(m);
    float ss = m * m;
    ss += __shfl_xor(ss, 16, 64); ss += __shfl_xor(ss, 8, 64);
    ss += __shfl_xor(ss, 4, 64);  ss += __shfl_xor(ss, 2, 64);
    ss += __shfl_xor(ss, 1, 64);
    float r = m / fmaxf(sqrtf(ss), 1e-12f);
    if (lane < 32) ws[OF_POOL + ((size_t)g * N + i) * FE + f] = sane(r);
}

// split-column attention: lane owns a Q row; 4 waves/block each take 1/4 of the
// block's column chunk; per-block mask bitmap rebuilt in LDS from the row-CSR;
// wave partials combined through LDS; one (O,l) partial per block to ws.
// Scores bounded (|q.k|/8 + 1) so exp without max-subtraction is safe.
__global__ void __launch_bounds__(256, 2)
attn_kernel(float* __restrict__ ws, const int* __restrict__ eip,
            const int* __restrict__ ein, const uint32_t* __restrict__ iws){
    int tid = threadIdx.x, lane = tid & 63, wv = tid >> 6;
    int rg = blockIdx.x, ch = blockIdx.y, sg = blockIdx.z;
    const float* Q = ws + OF_QKV + (size_t)(sg * 3) * NF;
    const float* K = Q + NF;
    const float* V = K + NF;

    __shared__ uint32_t mask[64 * MW];   // 64 rows x JC cols, bit = edge|diag
    __shared__ float Oacc[64 * 65];      // padded: bank = (lane+d)%32
    __shared__ float Lacc[64];
    for (int k = tid; k < 64 * MW; k += 256) mask[k] = 0u;
    for (int k = tid; k < 64 * 65; k += 256) Oacc[k] = 0.f;
    if (tid < 64) Lacc[tid] = 0.f;
    __syncthreads();

    const int csr = sg ? 2 : 0;          // row-grouped CSR for this sign
    const uint32_t* P   = iws + OI_PTR + (size_t)csr * (N + 1);
    const uint32_t* Eid = iws + OI_EID + (size_t)csr * Eg;
    const int* ei = sg ? ein : eip;
    int cbase = ch * JC;
    {   // build mask: 4 threads per row walk its edge list
        int r = tid >> 2, sub = tid & 3;
        int i = rg * 64 + r;
        uint32_t p0 = P[i], p1 = P[i + 1];
        if (p1 > (uint32_t)Eg) p1 = Eg;
        if (p0 > p1) p0 = p1;
        for (uint32_t p = p0 + sub; p < p1; p += 4){
            uint32_t e = Eid[p]; if (e >= Eg) e = 0;
            int c = clampi(ei[Eg + e]);
            int lc = c - cbase;
            if ((unsigned)lc < (unsigned)JC) atomicOr(&mask[r * MW + (lc >> 5)], 1u << (lc & 31));
        }
        if (sub == 0){
            int li = i - cbase;          // diagonal
            if ((unsigned)li < (unsigned)JC) atomicOr(&mask[r * MW + (li >> 5)], 1u << (li & 31));
        }
    }
    __syncthreads();

    int i = rg * 64 + lane;
    float qv[64];
    const float* qr = Q + (size_t)i * D;
    #pragma unroll
    for (int d = 0; d < 64; ++d) qv[d] = sane(qr[d]) * 0.125f;   // fold scale into q
    float Oa[64];
    #pragma unroll
    for (int d = 0; d < 64; ++d) Oa[d] = 0.f;
    float l = 0.f;

    constexpr int WC = JC / 4;           // cols per wave
    int j0 = cbase + wv * WC;
    int mbase = (wv * WC) >> 5;
    for (int jw = 0; jw < WC / 32; ++jw){
        uint32_t mw = mask[lane * MW + mbase + jw];
        int jb = j0 + jw * 32;
        for (int jj = 0; jj < 32; ++jj){
            const float* kr = K + (size_t)(jb + jj) * D;
            float s = 0.f;
            #pragma unroll
            for (int d = 0; d < 64; ++d) s += qv[d] * kr[d];
            s += ((mw >> jj) & 1u) ? 0.f : 1.f;   // additive mask: +1 off-edge/off-diag
            float p = __expf(fminf(s, 30.f));     // clamp: mathematically a no-op
            l += p;
            const float* vr = V + (size_t)(jb + jj) * D;
            #pragma unroll
            for (int d = 0; d < 64; ++d) Oa[d] += p * vr[d];
        }
    }

    #pragma unroll
    for (int d = 0; d < 64; ++d) atomicAdd(&Oacc[lane * 65 + d], sane(Oa[d]));
    atomicAdd(&Lacc[lane], sane(l));
    __syncthreads();

    float* Op = ws + OF_OPART + ((size_t)(sg * CH + ch) * N) * D;
    for (int k = tid; k < 64 * 64; k += 256){
        int r = k >> 6, d = k & 63;
        Op[(size_t)(rg * 64 + r) * D + d] = Oacc[r * 65 + d];
    }
    if (tid < 64) ws[OF_LPART + (size_t)(sg * CH + ch) * N + rg * 64 + tid] = Lacc[tid];
}

// fuse: chunk merge -> O@Wo+bo -> +mean -> concat feat -> feat@weight+bias -> row L2 norm
__global__ void final_kernel(const void* __restrict__ x1, const void* __restrict__ x2,
                             const void* __restrict__ Wo_p, const void* __restrict__ bo_p,
                             const void* __restrict__ Wo_n, const void* __restrict__ bo_n,
                             const void* __restrict__ weight, const void* __restrict__ bias,
                             const uint32_t* __restrict__ flags,
                             const float* __restrict__ ws, void* __restrict__ outv){
    uint32_t fA = flags[0], fC = flags[2], fD = flags[3];
    int wid = threadIdx.x >> 6, c = threadIdx.x & 63;
    int i = blockIdx.x * 4 + wid;
    __shared__ float feat[4][384];
    __shared__ float onrm[4][64];
    for (int s = 0; s < 2; ++s){
        float osum = 0.f, lsum = 0.f;
        for (int chh = 0; chh < CH; ++chh){
            osum += ws[OF_OPART + ((size_t)(s * CH + chh) * N + i) * D + c];
            lsum += ws[OF_LPART + (size_t)(s * CH + chh) * N + i];
        }
        onrm[wid][c] = sane(osum / fmaxf(lsum, 1e-20f));
        __syncthreads();
        const void* Wo = s ? Wo_n : Wo_p;
        const void* bo = s ? bo_n : bo_p;
        float attn = ldf(bo, c, fD);
        #pragma unroll 8
        for (int d = 0; d < 64; ++d) attn += onrm[wid][d] * ldf(Wo, (size_t)d * 64 + c, fD);
        feat[wid][s * 64 + c] = sane(ws[OF_MEAN + (size_t)s * NF + (size_t)i * D + c] + attn);
        __syncthreads();
    }
    feat[wid][128 + c] = sane(ldf(x1, (size_t)i * D + c, fA));
    feat[wid][192 + c] = sane(ldf(x2, (size_t)i * D + c, fA));
    {
        int g0 = c >> 5, f = c & 31;
        feat[wid][256 + c] = sane(ws[OF_POOL + ((size_t)g0 * N + i) * FE + f]);
        feat[wid][320 + c] = sane(ws[OF_POOL + ((size_t)(2 + g0) * N + i) * FE + f]);
    }
    __syncthreads();
    float acc = ldf(bias, c, fC);
    #pragma unroll 8
    for (int k = 0; k < 384; ++k) acc += feat[wid][k] * ldf(weight, (size_t)k * 64 + c, fC);
    acc = sane(acc);
    float ss = acc * acc;
    ss += __shfl_xor(ss, 32, 64); ss += __shfl_xor(ss, 16, 64); ss += __shfl_xor(ss, 8, 64);
    ss += __shfl_xor(ss, 4, 64);  ss += __shfl_xor(ss, 2, 64);  ss += __shfl_xor(ss, 1, 64);
    float r = acc / fmaxf(sqrtf(ss), 1e-12f);
    if (fA) ((float*)outv)[(size_t)i * D + c] = r;
    else    ((bf*)outv)[(size_t)i * D + c] = __float2bfloat16(r);
}

extern "C" void kernel_launch(void* const* d_in, const int* in_sizes, int n_in,
                              void* d_out, int out_size, void* d_ws, size_t ws_size,
                              hipStream_t stream){
    const int* eip = (const int*)d_in[2];
    const int* ein = (const int*)d_in[3];

    float* ws = (float*)d_ws;
    uint32_t* iws = (uint32_t*)(ws + F_TOTAL);
    uint32_t* flags = iws + OI_FLAG;

    zero_kernel<<<dim3((4 * N + 255) / 256), 256, 0, stream>>>(iws + OI_CNT, 4 * N);
    sniff_kernel<<<1, 256, 0, stream>>>(d_in[0], d_in[4], d_in[6], d_in[8], flags);

    qkv_kernel<<<dim3(N / 4, 6), 256, 0, stream>>>(
        d_in[0], d_in[1],
        d_in[8],  d_in[10], d_in[12],   // Wq_p, Wk_p, Wv_p
        d_in[16], d_in[18], d_in[20],   // Wq_n, Wk_n, Wv_n
        d_in[9],  d_in[11], d_in[13],   // bq_p, bk_p, bv_p
        d_in[17], d_in[19], d_in[21],   // bq_n, bk_n, bv_n
        flags, ws);
    count_kernel<<<dim3((Eg + 255) / 256), 256, 0, stream>>>(eip, ein, iws);
    scan_kernel<<<4, 256, 0, stream>>>(iws);
    fill_kernel<<<dim3((Eg + 255) / 256), 256, 0, stream>>>(eip, ein, iws);
    mean_kernel<<<dim3(2 * N / 4), 256, 0, stream>>>(d_in[0], d_in[1], eip, ein, iws, flags, ws);
    pool_kernel<<<dim3(4 * N / 4), 256, 0, stream>>>(d_in[4], d_in[5], iws, flags, ws);
    attn_kernel<<<dim3(RG, CH, 2), 256, 0, stream>>>(ws, eip, ein, iws);

    final_kernel<<<dim3(N / 4), 256, 0, stream>>>(
        d_in[0], d_in[1],
        d_in[14], d_in[15],   // Wo_p, bo_p
        d_in[22], d_in[23],   // Wo_n, bo_n
        d_in[6],  d_in[7],    // weight, bias
        flags, ws, d_out);
}

// Round 5
// 552.178 us; speedup vs baseline: 3.6966x; 3.6966x over previous
//
#include <hip/hip_runtime.h>
#include <hip/hip_bf16.h>
#include <stdint.h>

typedef __hip_bfloat16 bf;
typedef __attribute__((ext_vector_type(8))) short short8;
typedef __attribute__((ext_vector_type(4))) float float4v;
__device__ __forceinline__ float b2f(bf x){ return __bfloat162float(x); }
__device__ __forceinline__ float sane(float x){ return fminf(fmaxf(x, -1e6f), 1e6f); }
// f32 -> bf16 bits, round-to-nearest-even
__device__ __forceinline__ short f2b(float f){
    uint32_t u = __float_as_uint(f);
    u += 0x7fffu + ((u >> 16) & 1u);
    return (short)(u >> 16);
}

// Problem constants (fixed by the reference)
constexpr int N   = 6144;          // NOT a power of two (3*2^11)!
constexpr int D   = 64;
constexpr int FE  = 32;
constexpr int Eg  = 196608;
constexpr size_t NF = (size_t)N * D;

__device__ __forceinline__ int clampi(int v){ return v < 0 ? 0 : (v >= N ? N - 1 : v); }
__device__ __forceinline__ float ldf(const void* p, size_t i, uint32_t isf32){
    return isf32 ? ((const float*)p)[i] : b2f(((const bf*)p)[i]);
}

// ---- float workspace layout (floats) ----  ~14.3 MB
constexpr size_t OF_O    = 0;                             // [2][N][D] f32 attn numerator (atomic)
constexpr size_t OF_L    = OF_O + 2*NF;                   // [2][N]    f32 attn denominator (atomic)
constexpr size_t OF_MEAN = OF_L + 2*(size_t)N;            // [2][N][D]
constexpr size_t OF_POOL = OF_MEAN + 2*NF;                // [4][N][FE]
constexpr size_t OF_QKVB = OF_POOL + (size_t)4*N*FE;      // bf16 [2][3][N][D] (Q pre-scaled 0.125)
constexpr size_t F_TOTAL = OF_QKVB + 3*NF;                // 6*NF halfs = 3*NF float slots
// ---- u32 workspace (words, after float region) ----  ~3.44 MB
constexpr size_t OI_CNT  = 0;                             // [4][N]
constexpr size_t OI_PTR  = OI_CNT + 4*(size_t)N;          // [4][N+1]
constexpr size_t OI_CUR  = OI_PTR + 4*(size_t)(N+1);      // [4][N]
constexpr size_t OI_EID  = OI_CUR + 4*(size_t)N;          // [4][Eg]
constexpr size_t OI_FLAG = OI_EID + 4*(size_t)Eg;         // [4] dtype flags

__global__ void zero_kernel(float* __restrict__ p, int n){
    int i = blockIdx.x * 256 + threadIdx.x;
    if (i < n) p[i] = 0.f;
}
__global__ void zero_u32_kernel(uint32_t* __restrict__ p, int n){
    int i = blockIdx.x * 256 + threadIdx.x;
    if (i < n) p[i] = 0u;
}

// dtype sniff (proven in round 4): f32 misread as bf16 -> huge magnitudes
__global__ void sniff_kernel(const void* xA, const void* xB, const void* xC, const void* xD,
                             uint32_t* __restrict__ flags){
    __shared__ float red[256];
    const void* ps[4] = {xA, xB, xC, xD};
    int t = threadIdx.x;
    for (int k = 0; k < 4; ++k){
        const bf* p = (const bf*)ps[k];
        float m = 0.f;
        for (int i = t; i < 4096; i += 256){
            float v = fabsf(b2f(p[i]));
            if (!(v <= 1e9f)) v = 1e9f;
            m = fmaxf(m, v);
        }
        red[t] = m; __syncthreads();
        for (int off = 128; off; off >>= 1){
            if (t < off) red[t] = fmaxf(red[t], red[t + off]);
            __syncthreads();
        }
        if (t == 0) flags[k] = (red[0] > 100.f) ? 1u : 0u;
        __syncthreads();
    }
}

// QKV projections -> bf16 slabs (Q pre-scaled by 1/8)
__global__ void qkv_kernel(const void* __restrict__ x1, const void* __restrict__ x2,
                           const void* __restrict__ W0, const void* __restrict__ W1,
                           const void* __restrict__ W2, const void* __restrict__ W3,
                           const void* __restrict__ W4, const void* __restrict__ W5,
                           const void* __restrict__ B0, const void* __restrict__ B1,
                           const void* __restrict__ B2, const void* __restrict__ B3,
                           const void* __restrict__ B4, const void* __restrict__ B5,
                           const uint32_t* __restrict__ flags, float* __restrict__ ws){
    uint32_t fA = flags[0], fD = flags[3];
    int m = blockIdx.y;
    int wid = threadIdx.x >> 6, lane = threadIdx.x & 63;
    int i = blockIdx.x * 4 + wid;
    const void* x = (m < 3) ? x1 : x2;
    const void* W = (m==0)?W0:(m==1)?W1:(m==2)?W2:(m==3)?W3:(m==4)?W4:W5;
    const void* B = (m==0)?B0:(m==1)?B1:(m==2)?B2:(m==3)?B3:(m==4)?B4:B5;
    float acc = ldf(B, lane, fD);
    #pragma unroll 8
    for (int d = 0; d < D; ++d)
        acc += ldf(x, (size_t)i * D + d, fA) * ldf(W, (size_t)d * D + lane, fD);
    acc = sane(acc);
    if (m == 0 || m == 3) acc *= 0.125f;   // fold softmax scale into Q
    bf* qkvb = (bf*)(ws + OF_QKVB);
    qkvb[(size_t)m * NF + (size_t)i * D + lane] = __float2bfloat16(acc);
}

// ---- CSR build (unchanged from round 4) ----
__global__ void count_kernel(const int* __restrict__ eip, const int* __restrict__ ein,
                             uint32_t* __restrict__ iws){
    int e = blockIdx.x * 256 + threadIdx.x;
    if (e >= Eg) return;
    uint32_t* cnt = iws + OI_CNT;
    atomicAdd(&cnt[0 * N + clampi(eip[e])],      1u);
    atomicAdd(&cnt[1 * N + clampi(eip[Eg + e])], 1u);
    atomicAdd(&cnt[2 * N + clampi(ein[e])],      1u);
    atomicAdd(&cnt[3 * N + clampi(ein[Eg + e])], 1u);
}
__global__ void scan_kernel(uint32_t* __restrict__ iws){
    int b = blockIdx.x, t = threadIdx.x;
    const uint32_t* c = iws + OI_CNT + (size_t)b * N;
    uint32_t* P  = iws + OI_PTR + (size_t)b * (N + 1);
    uint32_t* Cu = iws + OI_CUR + (size_t)b * N;
    constexpr int K = N / 256;
    int base = t * K;
    uint32_t s = 0;
    for (int k = 0; k < K; ++k) s += c[base + k];
    __shared__ uint32_t sums[256];
    sums[t] = s; __syncthreads();
    for (int off = 1; off < 256; off <<= 1){
        uint32_t v = (t >= off) ? sums[t - off] : 0u;
        __syncthreads();
        sums[t] += v;
        __syncthreads();
    }
    uint32_t run = (t == 0) ? 0u : sums[t - 1];
    for (int k = 0; k < K; ++k){ P[base + k] = run; Cu[base + k] = run; run += c[base + k]; }
    if (t == 255) P[N] = run;
}
__global__ void fill_kernel(const int* __restrict__ eip, const int* __restrict__ ein,
                            uint32_t* __restrict__ iws){
    int e = blockIdx.x * 256 + threadIdx.x;
    if (e >= Eg) return;
    uint32_t* Cu  = iws + OI_CUR;
    uint32_t* Eid = iws + OI_EID;
    int rp = clampi(eip[e]), cp = clampi(eip[Eg + e]);
    int rn = clampi(ein[e]), cn = clampi(ein[Eg + e]);
    uint32_t p;
    p = atomicAdd(&Cu[0 * N + rp], 1u); if (p < Eg) Eid[0 * (size_t)Eg + p] = (uint32_t)e;
    p = atomicAdd(&Cu[1 * N + cp], 1u); if (p < Eg) Eid[1 * (size_t)Eg + p] = (uint32_t)e;
    p = atomicAdd(&Cu[2 * N + rn], 1u); if (p < Eg) Eid[2 * (size_t)Eg + p] = (uint32_t)e;
    p = atomicAdd(&Cu[3 * N + cn], 1u); if (p < Eg) Eid[3 * (size_t)Eg + p] = (uint32_t)e;
}

// neighbor mean (with self loop)
__global__ void mean_kernel(const void* __restrict__ x1, const void* __restrict__ x2,
                            const int* __restrict__ eip, const int* __restrict__ ein,
                            const uint32_t* __restrict__ iws,
                            const uint32_t* __restrict__ flags, float* __restrict__ ws){
    uint32_t fA = flags[0];
    int wid = threadIdx.x >> 6, d = threadIdx.x & 63;
    int gw = blockIdx.x * 4 + wid;
    int sign = gw >= N;
    int i = gw - sign * N;
    const void* x = sign ? x2 : x1;
    const int* ei = sign ? ein : eip;
    int csr = sign ? 2 : 0;
    const uint32_t* P   = iws + OI_PTR + (size_t)csr * (N + 1);
    const uint32_t* Eid = iws + OI_EID + (size_t)csr * Eg;
    float acc = ldf(x, (size_t)i * D + d, fA);
    uint32_t p0 = P[i], p1 = P[i + 1];
    if (p1 > (uint32_t)Eg) p1 = Eg;
    if (p0 > p1) p0 = p1;
    for (uint32_t p = p0; p < p1; ++p){
        uint32_t e = Eid[p]; if (e >= Eg) e = 0;
        int c = clampi(ei[Eg + e]);
        acc += ldf(x, (size_t)c * D + d, fA);
    }
    ws[OF_MEAN + (size_t)sign * NF + (size_t)i * D + d] = sane(acc / (float)(p1 - p0 + 1));
}

// per-node max-pool of edge features + L2 normalize
__global__ void pool_kernel(const void* __restrict__ efp, const void* __restrict__ efn,
                            const uint32_t* __restrict__ iws,
                            const uint32_t* __restrict__ flags, float* __restrict__ ws){
    uint32_t fB = flags[1];
    int wid = threadIdx.x >> 6, lane = threadIdx.x & 63;
    int gw = blockIdx.x * 4 + wid;
    int g = gw / N, i = gw - g * N;
    const void* ef = (g < 2) ? efp : efn;
    const uint32_t* P   = iws + OI_PTR + (size_t)g * (N + 1);
    const uint32_t* Eid = iws + OI_EID + (size_t)g * Eg;
    int f = lane & 31, h = lane >> 5;
    float m = 0.f;
    uint32_t p0 = P[i], p1 = P[i + 1];
    if (p1 > (uint32_t)Eg) p1 = Eg;
    if (p0 > p1) p0 = p1;
    for (uint32_t p = p0 + h; p < p1; p += 2){
        uint32_t e = Eid[p]; if (e >= Eg) e = 0;
        m = fmaxf(m, ldf(ef, (size_t)e * FE + f, fB));
    }
    m = fmaxf(m, __shfl_xor(m, 32, 64));
    m = sane(m);
    float ss = m * m;
    ss += __shfl_xor(ss, 16, 64); ss += __shfl_xor(ss, 8, 64);
    ss += __shfl_xor(ss, 4, 64);  ss += __shfl_xor(ss, 2, 64);
    ss += __shfl_xor(ss, 1, 64);
    float r = m / fmaxf(sqrtf(ss), 1e-12f);
    if (lane < 32) ws[OF_POOL + ((size_t)g * N + i) * FE + f] = sane(r);
}

// Dense UNMASKED attention via bf16 MFMA (mask handled by attn_corr_kernel).
// p = exp(s + 1) for every pair; S^T tiles so lane&15 = q-row throughout.
// Per block: 64 q-rows (4 waves x 16) x 1536 cols (1/4 split), K/V staged in LDS.
__global__ void __launch_bounds__(256, 3)
attn_dense_kernel(const bf* __restrict__ qkvb, float* __restrict__ O,
                  float* __restrict__ Lg){
    constexpr int KP = 72;   // K_lds pitch (halfs): bank spread + 16B-aligned rows
    constexpr int VP = 72;   // V_lds pitch (halfs)
    constexpr int PP = 36;   // P_lds pitch (f32 words)
    __shared__ __align__(16) short Kl[64 * KP];
    __shared__ __align__(16) short Vl[64 * VP];
    __shared__ __align__(16) float Pl[4][16 * PP];

    int tid = threadIdx.x, lane = tid & 63, wv = tid >> 6;
    int m16 = lane & 15, quad = lane >> 4;
    int rt = blockIdx.x, cs = blockIdx.y, sg = blockIdx.z;
    const bf* Qb = qkvb + (size_t)(sg * 3) * NF;
    const bf* Kb = Qb + NF;
    const bf* Vb = Kb + NF;

    int rowbase = rt * 64 + wv * 16;
    // persistent Q B-fragments: B[k=quad*8+j][n=lane&15] = Q[rowbase+m16][kh*32+quad*8+j]
    short8 Qf0 = *(const short8*)(Qb + (size_t)(rowbase + m16) * 64 + quad * 8);
    short8 Qf1 = *(const short8*)(Qb + (size_t)(rowbase + m16) * 64 + 32 + quad * 8);

    float4v Oc[4];
    #pragma unroll
    for (int t = 0; t < 4; ++t) Oc[t] = (float4v){0.f, 0.f, 0.f, 0.f};
    float l = 0.f;

    int scol = tid & 63, sgrp = tid >> 6;
    int c0 = cs * (N / 4), c1 = c0 + N / 4;
    for (int cb = c0; cb < c1; cb += 64){
        // stage K [col][k] and V^T [dim][col] (bf16)
        {
            const short* ksrc = (const short*)(Kb + (size_t)(cb + scol) * 64 + sgrp * 16);
            *(short8*)(&Kl[scol * KP + sgrp * 16])     = *(const short8*)(ksrc);
            *(short8*)(&Kl[scol * KP + sgrp * 16 + 8]) = *(const short8*)(ksrc + 8);
            const short* vsrc = (const short*)(Vb + (size_t)(cb + scol) * 64 + sgrp * 16);
            short8 v0 = *(const short8*)(vsrc);
            short8 v1 = *(const short8*)(vsrc + 8);
            #pragma unroll
            for (int j = 0; j < 8; ++j) Vl[(sgrp * 16 + j) * VP + scol] = v0[j];
            #pragma unroll
            for (int j = 0; j < 8; ++j) Vl[(sgrp * 16 + 8 + j) * VP + scol] = v1[j];
        }
        __syncthreads();

        float* Pw = Pl[wv];
        #pragma unroll
        for (int kg = 0; kg < 2; ++kg){
            #pragma unroll
            for (int ct = 0; ct < 2; ++ct){
                int colt = kg * 32 + ct * 16;
                // A-frag: A[m=lane&15][k=quad*8+j] = K[cb+colt+m16][k]
                short8 A0 = *(const short8*)(&Kl[(colt + m16) * KP + quad * 8]);
                short8 A1 = *(const short8*)(&Kl[(colt + m16) * KP + 32 + quad * 8]);
                float4v s = __builtin_amdgcn_mfma_f32_16x16x32_bf16(
                                A0, Qf0, (float4v){0.f,0.f,0.f,0.f}, 0, 0, 0);
                s = __builtin_amdgcn_mfma_f32_16x16x32_bf16(A1, Qf1, s, 0, 0, 0);
                // D[r=col_off][c=qrow]: c=lane&15 (qrow), r=quad*4+reg (col)
                #pragma unroll
                for (int r = 0; r < 4; ++r){
                    float p = __expf(s[r] + 1.0f);
                    l += p;
                    Pw[m16 * PP + ct * 16 + quad * 4 + r] = p;
                }
            }
            asm volatile("s_waitcnt lgkmcnt(0)" ::: "memory");
            // B-frag of P^T: B[k=quad*8+j][n=lane&15=qrow] = P[qrow][col k]
            float4v pa = *(const float4v*)(&Pw[m16 * PP + quad * 8]);
            float4v pb = *(const float4v*)(&Pw[m16 * PP + quad * 8 + 4]);
            short8 Pf;
            #pragma unroll
            for (int j = 0; j < 4; ++j){ Pf[j] = f2b(pa[j]); Pf[4 + j] = f2b(pb[j]); }
            #pragma unroll
            for (int dt = 0; dt < 4; ++dt){
                // A-frag: A[m=dim_off][k=col] = V^T[dt*16+m16][kg*32+quad*8+j]
                short8 Va = *(const short8*)(&Vl[(dt * 16 + m16) * VP + kg * 32 + quad * 8]);
                Oc[dt] = __builtin_amdgcn_mfma_f32_16x16x32_bf16(Va, Pf, Oc[dt], 0, 0, 0);
            }
        }
        __syncthreads();
    }
    // l: lane&15 = qrow; partials live across quads -> reduce, quad 0 writes
    l += __shfl_xor(l, 16, 64);
    l += __shfl_xor(l, 32, 64);
    if (quad == 0) atomicAdd(&Lg[(size_t)sg * N + rowbase + m16], l);
    // O^T frags: row = rowbase+m16, dim = dt*16 + quad*4 + r
    float* Op = O + ((size_t)sg * N + rowbase + m16) * 64;
    #pragma unroll
    for (int dt = 0; dt < 4; ++dt)
        #pragma unroll
        for (int r = 0; r < 4; ++r)
            atomicAdd(&Op[dt * 16 + quad * 4 + r], Oc[dt][r]);
}

// Sparse mask correction: for each edge (and the diagonal), subtract
// (1 - 1/e) * exp(s+1) from l and (1 - 1/e) * exp(s+1) * V[c][:] from O.
__global__ void attn_corr_kernel(const bf* __restrict__ qkvb,
                                 const int* __restrict__ eip, const int* __restrict__ ein,
                                 const uint32_t* __restrict__ iws,
                                 float* __restrict__ O, float* __restrict__ Lg){
    int wid = threadIdx.x >> 6, d = threadIdx.x & 63;
    int gw = blockIdx.x * 4 + wid;
    int sg = gw >= N;
    int i = gw - sg * N;
    const bf* Qb = qkvb + (size_t)(sg * 3) * NF;
    const bf* Kb = Qb + NF;
    const bf* Vb = Kb + NF;
    const int csr = sg ? 2 : 0;
    const uint32_t* Pp  = iws + OI_PTR + (size_t)csr * (N + 1);
    const uint32_t* Eid = iws + OI_EID + (size_t)csr * Eg;
    const int* ei = sg ? ein : eip;
    float q = b2f(Qb[(size_t)i * 64 + d]);   // pre-scaled by 1/8
    float corrO = 0.f, corrL = 0.f;
    uint32_t p0 = Pp[i], p1 = Pp[i + 1];
    if (p1 > (uint32_t)Eg) p1 = Eg;
    if (p0 > p1) p0 = p1;
    for (uint32_t p = p0; p <= p1; ++p){     // p == p1 handles the diagonal
        int c;
        if (p == p1) c = i;
        else { uint32_t e = Eid[p]; if (e >= Eg) e = 0; c = clampi(ei[Eg + e]); }
        float s = q * b2f(Kb[(size_t)c * 64 + d]);
        s += __shfl_xor(s, 32, 64); s += __shfl_xor(s, 16, 64); s += __shfl_xor(s, 8, 64);
        s += __shfl_xor(s, 4, 64);  s += __shfl_xor(s, 2, 64);  s += __shfl_xor(s, 1, 64);
        float f = 0.63212055882f * __expf(s + 1.0f);   // (1 - 1/e) * exp(s+1)
        corrO += f * b2f(Vb[(size_t)c * 64 + d]);
        corrL += f;
    }
    atomicAdd(&O[((size_t)sg * N + i) * 64 + d], -corrO);
    if (d == 0) atomicAdd(&Lg[(size_t)sg * N + i], -corrL);
}

// fuse: O/l -> O@Wo+bo -> +mean -> concat feat -> feat@weight+bias -> row L2 norm
__global__ void final_kernel(const void* __restrict__ x1, const void* __restrict__ x2,
                             const void* __restrict__ Wo_p, const void* __restrict__ bo_p,
                             const void* __restrict__ Wo_n, const void* __restrict__ bo_n,
                             const void* __restrict__ weight, const void* __restrict__ bias,
                             const uint32_t* __restrict__ flags,
                             const float* __restrict__ ws, void* __restrict__ outv){
    uint32_t fA = flags[0], fC = flags[2], fD = flags[3];
    int wid = threadIdx.x >> 6, c = threadIdx.x & 63;
    int i = blockIdx.x * 4 + wid;
    __shared__ float feat[4][384];
    __shared__ float onrm[4][64];
    for (int s = 0; s < 2; ++s){
        float osum = ws[OF_O + ((size_t)s * N + i) * 64 + c];
        float lsum = ws[OF_L + (size_t)s * N + i];
        onrm[wid][c] = sane(osum / fmaxf(lsum, 1e-20f));
        __syncthreads();
        const void* Wo = s ? Wo_n : Wo_p;
        const void* bo = s ? bo_n : bo_p;
        float attn = ldf(bo, c, fD);
        #pragma unroll 8
        for (int d = 0; d < 64; ++d) attn += onrm[wid][d] * ldf(Wo, (size_t)d * 64 + c, fD);
        feat[wid][s * 64 + c] = sane(ws[OF_MEAN + (size_t)s * NF + (size_t)i * D + c] + attn);
        __syncthreads();
    }
    feat[wid][128 + c] = sane(ldf(x1, (size_t)i * D + c, fA));
    feat[wid][192 + c] = sane(ldf(x2, (size_t)i * D + c, fA));
    {
        int g0 = c >> 5, f = c & 31;
        feat[wid][256 + c] = sane(ws[OF_POOL + ((size_t)g0 * N + i) * FE + f]);
        feat[wid][320 + c] = sane(ws[OF_POOL + ((size_t)(2 + g0) * N + i) * FE + f]);
    }
    __syncthreads();
    float acc = ldf(bias, c, fC);
    #pragma unroll 8
    for (int k = 0; k < 384; ++k) acc += feat[wid][k] * ldf(weight, (size_t)k * 64 + c, fC);
    acc = sane(acc);
    float ss = acc * acc;
    ss += __shfl_xor(ss, 32, 64); ss += __shfl_xor(ss, 16, 64); ss += __shfl_xor(ss, 8, 64);
    ss += __shfl_xor(ss, 4, 64);  ss += __shfl_xor(ss, 2, 64);  ss += __shfl_xor(ss, 1, 64);
    float r = acc / fmaxf(sqrtf(ss), 1e-12f);
    if (fA) ((float*)outv)[(size_t)i * D + c] = r;
    else    ((bf*)outv)[(size_t)i * D + c] = __float2bfloat16(r);
}

extern "C" void kernel_launch(void* const* d_in, const int* in_sizes, int n_in,
                              void* d_out, int out_size, void* d_ws, size_t ws_size,
                              hipStream_t stream){
    const int* eip = (const int*)d_in[2];
    const int* ein = (const int*)d_in[3];

    float* ws = (float*)d_ws;
    uint32_t* iws = (uint32_t*)(ws + F_TOTAL);
    uint32_t* flags = iws + OI_FLAG;
    bf* qkvb = (bf*)(ws + OF_QKVB);
    float* O  = ws + OF_O;
    float* Lg = ws + OF_L;

    int nzero = (int)(2 * NF + 2 * N);   // O + L contiguous
    zero_kernel<<<dim3((nzero + 255) / 256), 256, 0, stream>>>(O, nzero);
    zero_u32_kernel<<<dim3((4 * N + 255) / 256), 256, 0, stream>>>(iws + OI_CNT, 4 * N);
    sniff_kernel<<<1, 256, 0, stream>>>(d_in[0], d_in[4], d_in[6], d_in[8], flags);

    qkv_kernel<<<dim3(N / 4, 6), 256, 0, stream>>>(
        d_in[0], d_in[1],
        d_in[8],  d_in[10], d_in[12],   // Wq_p, Wk_p, Wv_p
        d_in[16], d_in[18], d_in[20],   // Wq_n, Wk_n, Wv_n
        d_in[9],  d_in[11], d_in[13],   // bq_p, bk_p, bv_p
        d_in[17], d_in[19], d_in[21],   // bq_n, bk_n, bv_n
        flags, ws);
    count_kernel<<<dim3((Eg + 255) / 256), 256, 0, stream>>>(eip, ein, iws);
    scan_kernel<<<4, 256, 0, stream>>>(iws);
    fill_kernel<<<dim3((Eg + 255) / 256), 256, 0, stream>>>(eip, ein, iws);
    mean_kernel<<<dim3(2 * N / 4), 256, 0, stream>>>(d_in[0], d_in[1], eip, ein, iws, flags, ws);
    pool_kernel<<<dim3(4 * N / 4), 256, 0, stream>>>(d_in[4], d_in[5], iws, flags, ws);

    attn_dense_kernel<<<dim3(N / 64, 4, 2), 256, 0, stream>>>(qkvb, O, Lg);
    attn_corr_kernel<<<dim3(2 * N / 4), 256, 0, stream>>>(qkvb, eip, ein, iws, O, Lg);

    final_kernel<<<dim3(N / 4), 256, 0, stream>>>(
        d_in[0], d_in[1],
        d_in[14], d_in[15],   // Wo_p, bo_p
        d_in[22], d_in[23],   // Wo_n, bo_n
        d_in[6],  d_in[7],    // weight, bias
        flags, ws, d_out);
}

// Round 6
// 432.728 us; speedup vs baseline: 4.7170x; 1.2760x over previous
//
#include <hip/hip_runtime.h>
#include <hip/hip_bf16.h>
#include <stdint.h>

typedef __hip_bfloat16 bf;
typedef __attribute__((ext_vector_type(8))) short short8;
typedef __attribute__((ext_vector_type(4))) float float4v;
__device__ __forceinline__ float b2f(bf x){ return __bfloat162float(x); }
__device__ __forceinline__ float sane(float x){ return fminf(fmaxf(x, -1e6f), 1e6f); }
__device__ __forceinline__ short f2b(float f){
    uint32_t u = __float_as_uint(f);
    u += 0x7fffu + ((u >> 16) & 1u);
    return (short)(u >> 16);
}

// Problem constants
constexpr int N   = 6144;          // NOT a power of two (3*2^11)!
constexpr int D   = 64;
constexpr int FE  = 32;
constexpr int Eg  = 196608;        // < 2^18 -> edge id packs in 18 bits
constexpr size_t NF = (size_t)N * D;

__device__ __forceinline__ int clampi(int v){ return v < 0 ? 0 : (v >= N ? N - 1 : v); }
__device__ __forceinline__ float ldf(const void* p, size_t i, uint32_t isf32){
    return isf32 ? ((const float*)p)[i] : b2f(((const bf*)p)[i]);
}

// ---- float workspace layout (floats) ----  ~17.6 MB
constexpr size_t OF_O    = 0;                           // [2][N][D] attn numerator (atomic)
constexpr size_t OF_L    = OF_O + 2*NF;                 // [2][N]    attn denominator (atomic)
constexpr size_t OF_MEAN = OF_L + 2*(size_t)N;          // [2][N][D]
constexpr size_t OF_POOL = OF_MEAN + 2*NF;              // [4][N][FE]
constexpr size_t OF_QKVB = OF_POOL + (size_t)4*N*FE;    // bf16 [2][3][N][D] (Q pre-scaled)
constexpr size_t OF_XF   = OF_QKVB + 3*NF;              // [2][N][D] f32 staged x1,x2
constexpr size_t OF_WA   = OF_XF + 2*NF;                // [6][64][64] attn proj W (f32)
constexpr size_t OF_BA   = OF_WA + 24576;               // [6][64]
constexpr size_t OF_WO   = OF_BA + 384;                 // [2][64][64] Wo_p, Wo_n
constexpr size_t OF_BO   = OF_WO + 8192;                // [2][64]
constexpr size_t OF_WF   = OF_BO + 128;                 // [384][64] final weight
constexpr size_t OF_BF   = OF_WF + 24576;               // [64]
constexpr size_t F_TOTAL = OF_BF + 64;
// ---- u32 workspace (words, after float region) ----  ~3.44 MB
constexpr size_t OI_CNT  = 0;                           // [4][N]
constexpr size_t OI_PTR  = OI_CNT + 4*(size_t)N;        // [4][N+1]
constexpr size_t OI_CUR  = OI_PTR + 4*(size_t)(N+1);    // [4][N]
constexpr size_t OI_PAY  = OI_CUR + 4*(size_t)N;        // [4][Eg]  payload: e | (other<<18)
constexpr size_t OI_FLAG = OI_PAY + 4*(size_t)Eg;       // [4] dtype flags

__global__ void zero_all_kernel(float* __restrict__ fz, int nf,
                                uint32_t* __restrict__ uz, int nu,
                                uint32_t* __restrict__ fl){
    int i = blockIdx.x * 256 + threadIdx.x;
    if (i < nf) fz[i] = 0.f;
    if (i < nu) uz[i] = 0u;
    if (i < 4)  fl[i] = 0u;
}

// dtype sniff: f32 misread as bf16 -> huge magnitudes (proven round 4)
__global__ void sniff_kernel(const void* xA, const void* xB, const void* xC, const void* xD,
                             uint32_t* __restrict__ flags){
    __shared__ float red[256];
    const void* ps[4] = {xA, xB, xC, xD};
    int t = threadIdx.x;
    for (int k = 0; k < 4; ++k){
        const bf* p = (const bf*)ps[k];
        float m = 0.f;
        for (int i = t; i < 1024; i += 256){
            float v = fabsf(b2f(p[i]));
            if (!(v <= 1e9f)) v = 1e9f;
            m = fmaxf(m, v);
        }
        red[t] = m; __syncthreads();
        for (int off = 128; off; off >>= 1){
            if (t < off) red[t] = fmaxf(red[t], red[t + off]);
            __syncthreads();
        }
        if (t == 0) flags[k] = (red[0] > 100.f) ? 1u : 0u;
        __syncthreads();
    }
}

// convert all float tensors to f32 staging (y=0: x, y=1: attn W/b, y=2: final W/b)
__global__ void convert_kernel(const void* x1, const void* x2,
                               const void* W0, const void* W1, const void* W2,
                               const void* W3, const void* W4, const void* W5,
                               const void* B0, const void* B1, const void* B2,
                               const void* B3, const void* B4, const void* B5,
                               const void* Wop, const void* bop,
                               const void* Won, const void* bon,
                               const void* wgt, const void* bia,
                               const uint32_t* __restrict__ flags, float* __restrict__ ws){
    int y = blockIdx.y;
    size_t idx = (size_t)blockIdx.x * 256 + threadIdx.x;
    if (y == 0){
        uint32_t fA = flags[0];
        float v = (idx < NF) ? ldf(x1, idx, fA) : ldf(x2, idx - NF, fA);
        ws[OF_XF + idx] = sane(v);
    } else if (y == 1){
        if (idx >= 33280) return;
        uint32_t fD = flags[3];
        float v;
        if (idx < 24576){
            int m = (int)(idx >> 12), sub = (int)(idx & 4095);
            const void* W = (m==0)?W0:(m==1)?W1:(m==2)?W2:(m==3)?W3:(m==4)?W4:W5;
            v = ldf(W, sub, fD);
        } else if (idx < 24960){
            int m = (int)((idx - 24576) >> 6), sub = (int)(idx & 63);
            const void* B = (m==0)?B0:(m==1)?B1:(m==2)?B2:(m==3)?B3:(m==4)?B4:B5;
            v = ldf(B, sub, fD);
        } else if (idx < 33152){
            int k = (int)((idx - 24960) >> 12), sub = (int)(idx & 4095);
            v = ldf(k ? Won : Wop, sub, fD);
        } else {
            int k = (int)((idx - 33152) >> 6), sub = (int)(idx & 63);
            v = ldf(k ? bon : bop, sub, fD);
        }
        ws[OF_WA + idx] = sane(v);
    } else {
        if (idx >= 24640) return;
        uint32_t fC = flags[2];
        float v = (idx < 24576) ? ldf(wgt, idx, fC) : ldf(bia, idx - 24576, fC);
        ws[OF_WF + idx] = sane(v);
    }
}

// QKV projections from staged f32 x/W via shfl-broadcast GEMV -> bf16 slabs
__global__ void qkv_kernel(const float* __restrict__ ws_ro, float* __restrict__ ws){
    int m = blockIdx.y;
    int wid = threadIdx.x >> 6, lane = threadIdx.x & 63;
    int i = blockIdx.x * 4 + wid;
    const float* x = ws_ro + OF_XF + (m < 3 ? 0 : NF) + (size_t)i * 64;
    const float* W = ws_ro + OF_WA + (size_t)m * 4096;
    float xreg = x[lane];
    float acc = ws_ro[OF_BA + m * 64 + lane];
    #pragma unroll 16
    for (int d = 0; d < 64; ++d)
        acc += __shfl(xreg, d, 64) * W[d * 64 + lane];
    acc = sane(acc);
    if (m == 0 || m == 3) acc *= 0.125f;   // fold softmax scale into Q
    bf* qkvb = (bf*)(ws + OF_QKVB);
    qkvb[(size_t)m * NF + (size_t)i * 64 + lane] = __float2bfloat16(acc);
}

// ---- CSR build ----
__global__ void count_kernel(const int* __restrict__ eip, const int* __restrict__ ein,
                             uint32_t* __restrict__ iws){
    int e = blockIdx.x * 256 + threadIdx.x;
    if (e >= Eg) return;
    uint32_t* cnt = iws + OI_CNT;
    atomicAdd(&cnt[0 * N + clampi(eip[e])],      1u);
    atomicAdd(&cnt[1 * N + clampi(eip[Eg + e])], 1u);
    atomicAdd(&cnt[2 * N + clampi(ein[e])],      1u);
    atomicAdd(&cnt[3 * N + clampi(ein[Eg + e])], 1u);
}
__global__ void scan_kernel(uint32_t* __restrict__ iws){
    int b = blockIdx.x, t = threadIdx.x;
    const uint32_t* c = iws + OI_CNT + (size_t)b * N;
    uint32_t* P  = iws + OI_PTR + (size_t)b * (N + 1);
    uint32_t* Cu = iws + OI_CUR + (size_t)b * N;
    constexpr int K = N / 256;
    int base = t * K;
    uint32_t s = 0;
    for (int k = 0; k < K; ++k) s += c[base + k];
    __shared__ uint32_t sums[256];
    sums[t] = s; __syncthreads();
    for (int off = 1; off < 256; off <<= 1){
        uint32_t v = (t >= off) ? sums[t - off] : 0u;
        __syncthreads();
        sums[t] += v;
        __syncthreads();
    }
    uint32_t run = (t == 0) ? 0u : sums[t - 1];
    for (int k = 0; k < K; ++k){ P[base + k] = run; Cu[base + k] = run; run += c[base + k]; }
    if (t == 255) P[N] = run;
}
// payload = e | (other_endpoint << 18)
__global__ void fill_kernel(const int* __restrict__ eip, const int* __restrict__ ein,
                            uint32_t* __restrict__ iws){
    int e = blockIdx.x * 256 + threadIdx.x;
    if (e >= Eg) return;
    uint32_t* Cu  = iws + OI_CUR;
    uint32_t* Pay = iws + OI_PAY;
    int rp = clampi(eip[e]), cp = clampi(eip[Eg + e]);
    int rn = clampi(ein[e]), cn = clampi(ein[Eg + e]);
    uint32_t p;
    p = atomicAdd(&Cu[0 * N + rp], 1u); if (p < Eg) Pay[0 * (size_t)Eg + p] = (uint32_t)e | ((uint32_t)cp << 18);
    p = atomicAdd(&Cu[1 * N + cp], 1u); if (p < Eg) Pay[1 * (size_t)Eg + p] = (uint32_t)e | ((uint32_t)rp << 18);
    p = atomicAdd(&Cu[2 * N + rn], 1u); if (p < Eg) Pay[2 * (size_t)Eg + p] = (uint32_t)e | ((uint32_t)cn << 18);
    p = atomicAdd(&Cu[3 * N + cn], 1u); if (p < Eg) Pay[3 * (size_t)Eg + p] = (uint32_t)e | ((uint32_t)rn << 18);
}

// ---- mega kernel: mean (3072 blocks) + pool (6144) + corr (3072) ----
__device__ __forceinline__ void mean_role(int b, const uint32_t* __restrict__ iws,
                                          const float* __restrict__ ws_ro, float* __restrict__ ws){
    int wid = threadIdx.x >> 6, d = threadIdx.x & 63;
    int gw = b * 4 + wid;
    int sign = gw >= N;
    int i = gw - sign * N;
    const float* x = ws_ro + OF_XF + (size_t)sign * NF;
    int csr = sign ? 2 : 0;
    const uint32_t* P   = iws + OI_PTR + (size_t)csr * (N + 1);
    const uint32_t* Pay = iws + OI_PAY + (size_t)csr * Eg;
    float acc = x[(size_t)i * 64 + d];   // self loop
    uint32_t p0 = P[i], p1 = P[i + 1];
    if (p1 > (uint32_t)Eg) p1 = Eg;
    if (p0 > p1) p0 = p1;
    uint32_t p = p0;
    for (; p + 4 <= p1; p += 4){
        int c0 = (int)(Pay[p]     >> 18);
        int c1 = (int)(Pay[p + 1] >> 18);
        int c2 = (int)(Pay[p + 2] >> 18);
        int c3 = (int)(Pay[p + 3] >> 18);
        float a0 = x[(size_t)c0 * 64 + d], a1 = x[(size_t)c1 * 64 + d];
        float a2 = x[(size_t)c2 * 64 + d], a3 = x[(size_t)c3 * 64 + d];
        acc += (a0 + a1) + (a2 + a3);
    }
    for (; p < p1; ++p)
        acc += x[(size_t)(Pay[p] >> 18) * 64 + d];
    ws[OF_MEAN + (size_t)sign * NF + (size_t)i * 64 + d] = sane(acc / (float)(p1 - p0 + 1));
}

__device__ __forceinline__ void pool_role(int b, const void* __restrict__ efp,
                                          const void* __restrict__ efn,
                                          const uint32_t* __restrict__ iws,
                                          uint32_t fB, float* __restrict__ ws){
    int wid = threadIdx.x >> 6, lane = threadIdx.x & 63;
    int gw = b * 4 + wid;
    int g = gw / N, i = gw - g * N;
    const void* ef = (g < 2) ? efp : efn;
    const uint32_t* P   = iws + OI_PTR + (size_t)g * (N + 1);
    const uint32_t* Pay = iws + OI_PAY + (size_t)g * Eg;
    int f = lane & 31, h = lane >> 5;
    float m = 0.f;
    uint32_t p0 = P[i], p1 = P[i + 1];
    if (p1 > (uint32_t)Eg) p1 = Eg;
    if (p0 > p1) p0 = p1;
    uint32_t p = p0 + h;
    if (fB){
        const float* E = (const float*)ef;
        for (; p + 2 < p1; p += 4){
            uint32_t e0 = Pay[p] & 0x3FFFFu, e1 = Pay[p + 2] & 0x3FFFFu;
            m = fmaxf(m, fmaxf(E[(size_t)e0 * 32 + f], E[(size_t)e1 * 32 + f]));
        }
        for (; p < p1; p += 2)
            m = fmaxf(m, E[(size_t)(Pay[p] & 0x3FFFFu) * 32 + f]);
    } else {
        const bf* E = (const bf*)ef;
        for (; p + 2 < p1; p += 4){
            uint32_t e0 = Pay[p] & 0x3FFFFu, e1 = Pay[p + 2] & 0x3FFFFu;
            m = fmaxf(m, fmaxf(b2f(E[(size_t)e0 * 32 + f]), b2f(E[(size_t)e1 * 32 + f])));
        }
        for (; p < p1; p += 2)
            m = fmaxf(m, b2f(E[(size_t)(Pay[p] & 0x3FFFFu) * 32 + f]));
    }
    m = fmaxf(m, __shfl_xor(m, 32, 64));
    m = sane(m);
    float ss = m * m;
    ss += __shfl_xor(ss, 16, 64); ss += __shfl_xor(ss, 8, 64);
    ss += __shfl_xor(ss, 4, 64);  ss += __shfl_xor(ss, 2, 64);
    ss += __shfl_xor(ss, 1, 64);
    float r = m / fmaxf(sqrtf(ss), 1e-12f);
    if (lane < 32) ws[OF_POOL + ((size_t)g * N + i) * 32 + f] = sane(r);
}

__device__ __forceinline__ void corr_role(int b, const uint32_t* __restrict__ iws,
                                          const float* __restrict__ ws_ro,
                                          float* __restrict__ O, float* __restrict__ Lg){
    int wid = threadIdx.x >> 6, d = threadIdx.x & 63;
    int gw = b * 4 + wid;
    int sg = gw >= N;
    int i = gw - sg * N;
    const bf* Qb = (const bf*)(ws_ro + OF_QKVB) + (size_t)(sg * 3) * NF;
    const bf* Kb = Qb + NF;
    const bf* Vb = Kb + NF;
    const int csr = sg ? 2 : 0;
    const uint32_t* Pp  = iws + OI_PTR + (size_t)csr * (N + 1);
    const uint32_t* Pay = iws + OI_PAY + (size_t)csr * Eg;
    float q = b2f(Qb[(size_t)i * 64 + d]);   // pre-scaled by 1/8
    float corrO = 0.f, corrL = 0.f;
    uint32_t p0 = Pp[i], p1 = Pp[i + 1];
    if (p1 > (uint32_t)Eg) p1 = Eg;
    if (p0 > p1) p0 = p1;
    constexpr float C = 0.63212055882f;      // 1 - 1/e
    uint32_t p = p0;
    for (; p + 2 <= p1; p += 2){
        int c0 = (int)(Pay[p] >> 18), c1 = (int)(Pay[p + 1] >> 18);
        float s0 = q * b2f(Kb[(size_t)c0 * 64 + d]);
        float s1 = q * b2f(Kb[(size_t)c1 * 64 + d]);
        s0 += __shfl_xor(s0, 32, 64); s1 += __shfl_xor(s1, 32, 64);
        s0 += __shfl_xor(s0, 16, 64); s1 += __shfl_xor(s1, 16, 64);
        s0 += __shfl_xor(s0, 8, 64);  s1 += __shfl_xor(s1, 8, 64);
        s0 += __shfl_xor(s0, 4, 64);  s1 += __shfl_xor(s1, 4, 64);
        s0 += __shfl_xor(s0, 2, 64);  s1 += __shfl_xor(s1, 2, 64);
        s0 += __shfl_xor(s0, 1, 64);  s1 += __shfl_xor(s1, 1, 64);
        float f0 = C * __expf(s0 + 1.0f);
        float f1 = C * __expf(s1 + 1.0f);
        corrO += f0 * b2f(Vb[(size_t)c0 * 64 + d]) + f1 * b2f(Vb[(size_t)c1 * 64 + d]);
        corrL += f0 + f1;
    }
    for (int extra = 0; extra < 2; ++extra){
        int c;
        if (extra == 0){ if (p >= p1) continue; c = (int)(Pay[p] >> 18); }
        else c = i;                              // diagonal
        float s = q * b2f(Kb[(size_t)c * 64 + d]);
        s += __shfl_xor(s, 32, 64); s += __shfl_xor(s, 16, 64); s += __shfl_xor(s, 8, 64);
        s += __shfl_xor(s, 4, 64);  s += __shfl_xor(s, 2, 64);  s += __shfl_xor(s, 1, 64);
        float f = C * __expf(s + 1.0f);
        corrO += f * b2f(Vb[(size_t)c * 64 + d]);
        corrL += f;
    }
    atomicAdd(&O[((size_t)sg * N + i) * 64 + d], -corrO);
    if (d == 0) atomicAdd(&Lg[(size_t)sg * N + i], -corrL);
}

__global__ void mega_kernel(const void* __restrict__ efp, const void* __restrict__ efn,
                            const uint32_t* __restrict__ iws,
                            const uint32_t* __restrict__ flags, float* __restrict__ ws){
    int b = blockIdx.x;
    if (b < 3072)       mean_role(b, iws, ws, ws);
    else if (b < 9216)  pool_role(b - 3072, efp, efn, iws, flags[1], ws);
    else                corr_role(b - 9216, iws, ws, ws + OF_O, ws + OF_L);
}

// Dense UNMASKED attention via bf16 MFMA (verified round 5).
__global__ void __launch_bounds__(256, 3)
attn_dense_kernel(const bf* __restrict__ qkvb, float* __restrict__ O,
                  float* __restrict__ Lg){
    constexpr int KP = 72;
    constexpr int VP = 72;
    constexpr int PP = 36;
    __shared__ __align__(16) short Kl[64 * KP];
    __shared__ __align__(16) short Vl[64 * VP];
    __shared__ __align__(16) float Pl[4][16 * PP];

    int tid = threadIdx.x, lane = tid & 63, wv = tid >> 6;
    int m16 = lane & 15, quad = lane >> 4;
    int rt = blockIdx.x, cs = blockIdx.y, sg = blockIdx.z;
    const bf* Qb = qkvb + (size_t)(sg * 3) * NF;
    const bf* Kb = Qb + NF;
    const bf* Vb = Kb + NF;

    int rowbase = rt * 64 + wv * 16;
    short8 Qf0 = *(const short8*)(Qb + (size_t)(rowbase + m16) * 64 + quad * 8);
    short8 Qf1 = *(const short8*)(Qb + (size_t)(rowbase + m16) * 64 + 32 + quad * 8);

    float4v Oc[4];
    #pragma unroll
    for (int t = 0; t < 4; ++t) Oc[t] = (float4v){0.f, 0.f, 0.f, 0.f};
    float l = 0.f;

    int scol = tid & 63, sgrp = tid >> 6;
    int c0 = cs * (N / 4), c1 = c0 + N / 4;
    for (int cb = c0; cb < c1; cb += 64){
        {
            const short* ksrc = (const short*)(Kb + (size_t)(cb + scol) * 64 + sgrp * 16);
            *(short8*)(&Kl[scol * KP + sgrp * 16])     = *(const short8*)(ksrc);
            *(short8*)(&Kl[scol * KP + sgrp * 16 + 8]) = *(const short8*)(ksrc + 8);
            const short* vsrc = (const short*)(Vb + (size_t)(cb + scol) * 64 + sgrp * 16);
            short8 v0 = *(const short8*)(vsrc);
            short8 v1 = *(const short8*)(vsrc + 8);
            #pragma unroll
            for (int j = 0; j < 8; ++j) Vl[(sgrp * 16 + j) * VP + scol] = v0[j];
            #pragma unroll
            for (int j = 0; j < 8; ++j) Vl[(sgrp * 16 + 8 + j) * VP + scol] = v1[j];
        }
        __syncthreads();

        float* Pw = Pl[wv];
        #pragma unroll
        for (int kg = 0; kg < 2; ++kg){
            #pragma unroll
            for (int ct = 0; ct < 2; ++ct){
                int colt = kg * 32 + ct * 16;
                short8 A0 = *(const short8*)(&Kl[(colt + m16) * KP + quad * 8]);
                short8 A1 = *(const short8*)(&Kl[(colt + m16) * KP + 32 + quad * 8]);
                float4v s = __builtin_amdgcn_mfma_f32_16x16x32_bf16(
                                A0, Qf0, (float4v){0.f,0.f,0.f,0.f}, 0, 0, 0);
                s = __builtin_amdgcn_mfma_f32_16x16x32_bf16(A1, Qf1, s, 0, 0, 0);
                #pragma unroll
                for (int r = 0; r < 4; ++r){
                    float p = __expf(s[r] + 1.0f);
                    l += p;
                    Pw[m16 * PP + ct * 16 + quad * 4 + r] = p;
                }
            }
            asm volatile("s_waitcnt lgkmcnt(0)" ::: "memory");
            float4v pa = *(const float4v*)(&Pw[m16 * PP + quad * 8]);
            float4v pb = *(const float4v*)(&Pw[m16 * PP + quad * 8 + 4]);
            short8 Pf;
            #pragma unroll
            for (int j = 0; j < 4; ++j){ Pf[j] = f2b(pa[j]); Pf[4 + j] = f2b(pb[j]); }
            #pragma unroll
            for (int dt = 0; dt < 4; ++dt){
                short8 Va = *(const short8*)(&Vl[(dt * 16 + m16) * VP + kg * 32 + quad * 8]);
                Oc[dt] = __builtin_amdgcn_mfma_f32_16x16x32_bf16(Va, Pf, Oc[dt], 0, 0, 0);
            }
        }
        __syncthreads();
    }
    l += __shfl_xor(l, 16, 64);
    l += __shfl_xor(l, 32, 64);
    if (quad == 0) atomicAdd(&Lg[(size_t)sg * N + rowbase + m16], l);
    float* Op = O + ((size_t)sg * N + rowbase + m16) * 64;
    #pragma unroll
    for (int dt = 0; dt < 4; ++dt)
        #pragma unroll
        for (int r = 0; r < 4; ++r)
            atomicAdd(&Op[dt * 16 + quad * 4 + r], Oc[dt][r]);
}

// fuse: O/l -> O@Wo+bo -> +mean -> concat -> feat@weight+bias -> row L2 norm
__global__ void final_kernel(const uint32_t* __restrict__ flags,
                             const float* __restrict__ ws, void* __restrict__ outv){
    uint32_t fA = flags[0];
    int wid = threadIdx.x >> 6, c = threadIdx.x & 63;
    int i = blockIdx.x * 4 + wid;
    __shared__ float feat[4][384];
    __shared__ float onrm[4][64];
    for (int s = 0; s < 2; ++s){
        float osum = ws[OF_O + ((size_t)s * N + i) * 64 + c];
        float lsum = ws[OF_L + (size_t)s * N + i];
        onrm[wid][c] = sane(osum / fmaxf(lsum, 1e-20f));
        __syncthreads();
        const float* Wo = ws + OF_WO + (size_t)s * 4096;
        float attn = ws[OF_BO + s * 64 + c];
        #pragma unroll 8
        for (int d = 0; d < 64; ++d) attn += onrm[wid][d] * Wo[d * 64 + c];
        feat[wid][s * 64 + c] = sane(ws[OF_MEAN + (size_t)s * NF + (size_t)i * 64 + c] + attn);
        __syncthreads();
    }
    feat[wid][128 + c] = ws[OF_XF + (size_t)i * 64 + c];
    feat[wid][192 + c] = ws[OF_XF + NF + (size_t)i * 64 + c];
    {
        int g0 = c >> 5, f = c & 31;
        feat[wid][256 + c] = ws[OF_POOL + ((size_t)g0 * N + i) * 32 + f];
        feat[wid][320 + c] = ws[OF_POOL + ((size_t)(2 + g0) * N + i) * 32 + f];
    }
    __syncthreads();
    float acc = ws[OF_BF + c];
    #pragma unroll 8
    for (int k = 0; k < 384; ++k) acc += feat[wid][k] * ws[OF_WF + (size_t)k * 64 + c];
    acc = sane(acc);
    float ss = acc * acc;
    ss += __shfl_xor(ss, 32, 64); ss += __shfl_xor(ss, 16, 64); ss += __shfl_xor(ss, 8, 64);
    ss += __shfl_xor(ss, 4, 64);  ss += __shfl_xor(ss, 2, 64);  ss += __shfl_xor(ss, 1, 64);
    float r = acc / fmaxf(sqrtf(ss), 1e-12f);
    if (fA) ((float*)outv)[(size_t)i * 64 + c] = r;
    else    ((bf*)outv)[(size_t)i * 64 + c] = __float2bfloat16(r);
}

extern "C" void kernel_launch(void* const* d_in, const int* in_sizes, int n_in,
                              void* d_out, int out_size, void* d_ws, size_t ws_size,
                              hipStream_t stream){
    const int* eip = (const int*)d_in[2];
    const int* ein = (const int*)d_in[3];

    float* ws = (float*)d_ws;
    uint32_t* iws = (uint32_t*)(ws + F_TOTAL);
    uint32_t* flags = iws + OI_FLAG;
    bf* qkvb = (bf*)(ws + OF_QKVB);
    float* O  = ws + OF_O;
    float* Lg = ws + OF_L;

    int nf = (int)(2 * NF + 2 * N);       // O + L contiguous
    int nu = 4 * N;                        // CSR counts
    zero_all_kernel<<<dim3((nf + 255) / 256), 256, 0, stream>>>(O, nf, iws + OI_CNT, nu, flags);
    sniff_kernel<<<1, 256, 0, stream>>>(d_in[0], d_in[4], d_in[6], d_in[8], flags);
    convert_kernel<<<dim3(3072, 3), 256, 0, stream>>>(
        d_in[0], d_in[1],
        d_in[8],  d_in[10], d_in[12], d_in[16], d_in[18], d_in[20],
        d_in[9],  d_in[11], d_in[13], d_in[17], d_in[19], d_in[21],
        d_in[14], d_in[15], d_in[22], d_in[23],
        d_in[6],  d_in[7],
        flags, ws);
    count_kernel<<<dim3((Eg + 255) / 256), 256, 0, stream>>>(eip, ein, iws);
    scan_kernel<<<4, 256, 0, stream>>>(iws);
    fill_kernel<<<dim3((Eg + 255) / 256), 256, 0, stream>>>(eip, ein, iws);
    qkv_kernel<<<dim3(N / 4, 6), 256, 0, stream>>>(ws, ws);
    attn_dense_kernel<<<dim3(N / 64, 4, 2), 256, 0, stream>>>(qkvb, O, Lg);
    mega_kernel<<<dim3(12288), 256, 0, stream>>>(d_in[4], d_in[5], iws, flags, ws);
    final_kernel<<<dim3(N / 4), 256, 0, stream>>>(flags, ws, d_out);
}